// Round 1
// baseline (315.557 us; speedup 1.0000x reference)
//
#include <hip/hip_runtime.h>
#include <hip/hip_bf16.h>
#include <cstdint>
#include <cstddef>

typedef __hip_bfloat16 bf16;
typedef float  floatx4 __attribute__((ext_vector_type(4)));
typedef __bf16 bf16x8  __attribute__((ext_vector_type(8)));

typedef __attribute__((address_space(1))) void as1_void;
typedef __attribute__((address_space(3))) void as3_void;

constexpr int Bn = 4, Ln = 2048, Cn = 1024;

__device__ __forceinline__ void store_one(float* p, float v) { *p = v; }
__device__ __forceinline__ void store_one(bf16*  p, float v) { *p = __float2bfloat16(v); }

// ---------------------------------------------------------------------------
// Generic bf16 BT-GEMM: C[m][n] = sum_k A[m][k] * B[n][k]
// 128x128 tile / block (256 thr, 4 waves, each wave 64x64 = 4x4 mfma 16x16x32)
// CAUSAL: 0 = none, 1 = skip tiles with n0 > m0 (S=QK^T), 2 = clamp K to m0+128 (PV)
// ---------------------------------------------------------------------------
template <typename OutT, int CAUSAL>
__global__ __launch_bounds__(256)
void gemm_bt(const bf16* __restrict__ A, const bf16* __restrict__ B, OutT* __restrict__ C,
             int M, int N, int K, int lda, int ldb, int ldc,
             long long sA, long long sB, long long sC)
{
    const int bz = blockIdx.z;
    A += bz * sA;  B += bz * sB;  C += bz * sC;
    const int m0 = blockIdx.x * 128;
    const int n0 = blockIdx.y * 128;
    if (CAUSAL == 1 && n0 > m0) return;          // fully-masked tile, never read
    int Keff = K;
    if (CAUSAL == 2) Keff = (K < m0 + 128) ? K : (m0 + 128);

    __shared__ __align__(16) bf16 smem[2 * 128 * 32];   // As (8KB) then Bs (8KB)

    const int tid  = threadIdx.x;
    const int lane = tid & 63;
    const int quad = lane >> 4;      // 0..3
    const int lr   = lane & 15;      // row-in-16 for A/B frags; col for C
    const int wave = tid >> 6;
    const int wm   = (wave >> 1) * 64;
    const int wn   = (wave & 1) * 64;

    floatx4 acc[4][4];
#pragma unroll
    for (int i = 0; i < 4; ++i)
#pragma unroll
        for (int j = 0; j < 4; ++j) { floatx4 z = {0.f, 0.f, 0.f, 0.f}; acc[i][j] = z; }

    // staging plan: 16KB = 1024 x 16B chunks; chunk = it*256 + tid, LDS linear.
    // global_load_lds: LDS dest = wave-uniform base + lane*16 (contiguous lane order).
    const bf16* gbase[4];
    int ldsoff[4];
#pragma unroll
    for (int it = 0; it < 4; ++it) {
        int chunk = it * 256 + tid;
        ldsoff[it] = __builtin_amdgcn_readfirstlane((chunk & ~63) * 16);
        if (chunk < 512) {               // A side: 4 chunks per 32-elem row
            int m = chunk >> 2, kc = chunk & 3;
            gbase[it] = A + (size_t)(m0 + m) * lda + kc * 8;
        } else {                         // B side
            int c2 = chunk - 512;
            int n = c2 >> 2, kc = c2 & 3;
            gbase[it] = B + (size_t)(n0 + n) * ldb + kc * 8;
        }
    }

    for (int k0 = 0; k0 < Keff; k0 += 32) {
        __syncthreads();
#pragma unroll
        for (int it = 0; it < 4; ++it) {
            uintptr_t ga = (uintptr_t)(gbase[it] + k0);
            uintptr_t la = (uintptr_t)((char*)smem + ldsoff[it]);
            __builtin_amdgcn_global_load_lds((const as1_void*)ga, (as3_void*)la, 16, 0, 0);
        }
        __syncthreads();

        const bf16* As = smem;
        const bf16* Bs = smem + 128 * 32;
        bf16x8 afrag[4], bfrag[4];
#pragma unroll
        for (int i = 0; i < 4; ++i)
            afrag[i] = *(const bf16x8*)(As + (size_t)(wm + i * 16 + lr) * 32 + quad * 8);
#pragma unroll
        for (int j = 0; j < 4; ++j)
            bfrag[j] = *(const bf16x8*)(Bs + (size_t)(wn + j * 16 + lr) * 32 + quad * 8);
#pragma unroll
        for (int i = 0; i < 4; ++i)
#pragma unroll
            for (int j = 0; j < 4; ++j)
                acc[i][j] = __builtin_amdgcn_mfma_f32_16x16x32_bf16(afrag[i], bfrag[j], acc[i][j], 0, 0, 0);
    }

    // epilogue: C/D layout col=lane&15, row=quad*4+r  (m89-verified)
#pragma unroll
    for (int i = 0; i < 4; ++i) {
        int row = m0 + wm + i * 16 + quad * 4;
#pragma unroll
        for (int j = 0; j < 4; ++j) {
            int col = n0 + wn + j * 16 + lr;
            OutT* cp = C + (size_t)row * ldc + col;
#pragma unroll
            for (int r = 0; r < 4; ++r)
                store_one(cp + (size_t)r * ldc, acc[i][j][r]);
        }
    }
}

// ---------------------------------------------------------------------------
// Causal softmax, one block per row; writes bf16 P in place over fp32 S.
// Safe: all reads complete before the block reductions' barriers; writes after.
// ---------------------------------------------------------------------------
__device__ __forceinline__ float waveMax(float x) {
#pragma unroll
    for (int o = 32; o > 0; o >>= 1) x = fmaxf(x, __shfl_xor(x, o, 64));
    return x;
}
__device__ __forceinline__ float waveSum(float x) {
#pragma unroll
    for (int o = 32; o > 0; o >>= 1) x += __shfl_xor(x, o, 64);
    return x;
}

__global__ __launch_bounds__(256)
void softmax_causal(float* __restrict__ S, float scale)
{
    const long long row = blockIdx.x;            // b*L + q
    const int q = (int)(row & (Ln - 1));
    float* Srow = S + row * Ln;
    bf16*  Prow = (bf16*)Srow;
    const int tid = threadIdx.x;
    const int lane = tid & 63, wave = tid >> 6;

    float v[8];
    float m = -1e30f;
#pragma unroll
    for (int it = 0; it < 8; ++it) {
        int k = it * 256 + tid;
        float x = (k <= q) ? Srow[k] * scale : -1e30f;
        v[it] = x;
        m = fmaxf(m, x);
    }
    __shared__ float redm[4], reds[4];
    m = waveMax(m);
    if (lane == 0) redm[wave] = m;
    __syncthreads();
    m = fmaxf(fmaxf(redm[0], redm[1]), fmaxf(redm[2], redm[3]));

    float s = 0.f;
#pragma unroll
    for (int it = 0; it < 8; ++it) {
        float e = (v[it] <= -1e30f) ? 0.f : __expf(v[it] - m);
        v[it] = e;
        s += e;
    }
    s = waveSum(s);
    if (lane == 0) reds[wave] = s;
    __syncthreads();
    s = reds[0] + reds[1] + reds[2] + reds[3];
    float inv = 1.f / s;
#pragma unroll
    for (int it = 0; it < 8; ++it) {
        int k = it * 256 + tid;
        Prow[k] = __float2bfloat16(v[it] * inv);   // zeros beyond q -> PV sums cleanly
    }
}

// ---------------------------------------------------------------------------
// VT[b][c][l] = qkv[b][l][2C + c]   (32x32 tiles via LDS)
// ---------------------------------------------------------------------------
__global__ __launch_bounds__(256)
void transpose_v(const bf16* __restrict__ qkv, bf16* __restrict__ VT)
{
    __shared__ bf16 t[32][33];
    const int b = blockIdx.z;
    const int l0 = blockIdx.x * 32, c0 = blockIdx.y * 32;
    const int tx = threadIdx.x & 31, ty0 = threadIdx.x >> 5;   // ty0 in 0..7
    const bf16* src = qkv + ((size_t)(b * Ln + l0) * (3 * Cn)) + 2 * Cn + c0;
#pragma unroll
    for (int p = 0; p < 4; ++p) {
        int ly = ty0 + p * 8;
        t[ly][tx] = src[(size_t)ly * (3 * Cn) + tx];
    }
    __syncthreads();
    bf16* dst = VT + ((size_t)b * Cn + c0) * Ln + l0;
#pragma unroll
    for (int p = 0; p < 4; ++p) {
        int cy = ty0 + p * 8;
        dst[(size_t)cy * Ln + tx] = t[tx][cy];
    }
}

// ---------------------------------------------------------------------------
__global__ __launch_bounds__(256)
void cast_f32_bf16(const float* __restrict__ in, bf16* __restrict__ out, int n4)
{
    int i = blockIdx.x * 256 + threadIdx.x;
    if (i >= n4) return;
    float4 f = ((const float4*)in)[i];
    bf16 o0 = __float2bfloat16(f.x), o1 = __float2bfloat16(f.y);
    bf16 o2 = __float2bfloat16(f.z), o3 = __float2bfloat16(f.w);
    ushort4 u;
    u.x = *(unsigned short*)&o0; u.y = *(unsigned short*)&o1;
    u.z = *(unsigned short*)&o2; u.w = *(unsigned short*)&o3;
    *(ushort4*)(out + (size_t)i * 4) = u;
}

// ---------------------------------------------------------------------------
extern "C" void kernel_launch(void* const* d_in, const int* in_sizes, int n_in,
                              void* d_out, int out_size, void* d_ws, size_t ws_size,
                              hipStream_t stream)
{
    const float* X    = (const float*)d_in[0];   // (B,L,C)
    const float* Wqkv = (const float*)d_in[1];   // (3C,C)
    const float* Wout = (const float*)d_in[2];   // (C,C)
    float* out = (float*)d_out;                  // (B,L,C) fp32

    char* ws = (char*)d_ws;
    // ws layout (Xb aliases S: disjoint lifetimes)
    float* Sbuf = (float*)(ws + 0);                       // 4*2048*2048*4 = 64 MiB (P bf16 in place)
    bf16*  Xb   = (bf16*)(ws + 0);                        // 16 MiB, dead after GEMM1
    bf16*  QKV  = (bf16*)(ws + 67108864ull);              // 8192*3072*2 = 48 MiB
    bf16*  VT   = (bf16*)(ws + 67108864ull + 50331648ull);          // 16 MiB
    bf16*  Wqb  = (bf16*)(ws + 67108864ull + 50331648ull + 16777216ull);       // 6 MiB
    bf16*  Wob  = (bf16*)(ws + 67108864ull + 50331648ull + 16777216ull + 6291456ull); // 2 MiB
    bf16*  Obuf = (bf16*)(ws + 67108864ull + 50331648ull + 16777216ull + 6291456ull + 2097152ull); // 16 MiB

    // casts to bf16
    cast_f32_bf16<<<dim3(Bn*Ln*Cn/4/256), 256, 0, stream>>>(X, Xb, Bn*Ln*Cn/4);
    cast_f32_bf16<<<dim3(3*Cn*Cn/4/256), 256, 0, stream>>>(Wqkv, Wqb, 3*Cn*Cn/4);
    cast_f32_bf16<<<dim3(Cn*Cn/4/256), 256, 0, stream>>>(Wout, Wob, Cn*Cn/4);

    // 1) qkv = Xb @ Wqb^T   (8192 x 3072, K=1024)
    gemm_bt<bf16, 0><<<dim3(64, 24, 1), 256, 0, stream>>>(
        Xb, Wqb, QKV, 8192, 3072, 1024, 1024, 1024, 3072, 0, 0, 0);

    // V^T for the PV gemm
    transpose_v<<<dim3(Ln/32, Cn/32, Bn), 256, 0, stream>>>(QKV, VT);

    // 2) S = Q @ K^T per batch (skip strictly-upper 128-tiles)
    gemm_bt<float, 1><<<dim3(16, 16, Bn), 256, 0, stream>>>(
        QKV, QKV + Cn, Sbuf, Ln, Ln, Cn, 3*Cn, 3*Cn, Ln,
        (long long)Ln * 3 * Cn, (long long)Ln * 3 * Cn, (long long)Ln * Ln);

    // 3) causal softmax, P (bf16) written in place over S rows (ld = 4096 bf16)
    softmax_causal<<<dim3(Bn * Ln), 256, 0, stream>>>(Sbuf, 0.03125f);

    // 4) O = P @ VT^T per batch (K clamped to m0+128: P is zero beyond q)
    gemm_bt<bf16, 2><<<dim3(16, 8, Bn), 256, 0, stream>>>(
        (const bf16*)Sbuf, VT, Obuf, Ln, Cn, Ln, 2 * Ln, Ln, Cn,
        (long long)Ln * 2 * Ln, (long long)Cn * Ln, (long long)Ln * Cn);

    // 5) out = O @ Wob^T  (fp32 out)
    gemm_bt<float, 0><<<dim3(64, 8, 1), 256, 0, stream>>>(
        Obuf, Wob, out, Bn * Ln, Cn, Cn, Cn, Cn, Cn, 0, 0, 0);
}